// Round 1
// baseline (11250.644 us; speedup 1.0000x reference)
//
#include <hip/hip_runtime.h>
#include <hip/hip_fp16.h>

typedef _Float16 half8 __attribute__((ext_vector_type(8)));
typedef float floatx4 __attribute__((ext_vector_type(4)));

// Problem constants: B=128, T=512, E=256, H=512, OUT=9, L=2
// Layer quirk (faithful to reference): BOTH layers use Uk_w[0] / Uk_b[0].

// ---------------- generic f32 -> f16 cast ----------------
__global__ void cast_f32_f16(const float* __restrict__ src, _Float16* __restrict__ dst, int n) {
  int i = blockIdx.x * blockDim.x + threadIdx.x;
  if (i < n) dst[i] = (_Float16)src[i];
}

// ---------------- small prep: V pad 9->16 rows, fused biases, barrier init ----------------
__global__ void prep_small(const float* __restrict__ Vw, const float* __restrict__ Wb,
                           const float* __restrict__ Ukb, const float* __restrict__ Wkb,
                           _Float16* __restrict__ V16, float* __restrict__ bxp,
                           float* __restrict__ bc, unsigned* __restrict__ bar) {
  int i = blockIdx.x * blockDim.x + threadIdx.x;
  if (i < 16 * 512) {
    int o = i >> 9, k = i & 511;
    V16[i] = (_Float16)(o < 9 ? Vw[o * 512 + k] : 0.0f);
  }
  if (i < 512) {
    bxp[i] = Wb[i] + Ukb[i];   // layer-0 pre-activation bias
    bc[i]  = Wkb[i] + Ukb[i];  // layer-1 pre-activation bias (folded into c)
  }
  if (i < 128) bar[i] = 0u;    // 8 groups x 16 uints (cnt, epoch, pad)
}

// ---------------- tiled MFMA GEMM: C[M][512] = A[M][K] * B[512][K]^T + bias ----------------
// BM=128, BN=128, BK=32. 256 threads (4 waves); wave w: rows [w*32,w*32+32), all 128 cols.
// OUTMODE 0: out row = r. OUTMODE 1: out row = (r&511)*128 + (r>>9)  (emb [B][T] -> xp [T][B]).
template <bool A_FP32, int OUTMODE>
__global__ __launch_bounds__(256) void gemm_f16(const void* __restrict__ Aptr,
                                                const _Float16* __restrict__ Bw,
                                                _Float16* __restrict__ Cout,
                                                const float* __restrict__ bias, int K) {
  __shared__ __align__(16) _Float16 As[128][40];  // +8 pad: 2-way-max LDS banking
  __shared__ __align__(16) _Float16 Bs[128][40];
  const int tid = threadIdx.x;
  const int bm = blockIdx.x, bn = blockIdx.y;
  const int w = tid >> 6, lane = tid & 63;
  const int m = lane & 15, q = lane >> 4;

  floatx4 acc[2][8];
#pragma unroll
  for (int i = 0; i < 2; ++i)
#pragma unroll
    for (int j = 0; j < 8; ++j) acc[i][j] = (floatx4){0.f, 0.f, 0.f, 0.f};

  const int nk = K >> 5;
  for (int kt = 0; kt < nk; ++kt) {
    const int k0 = kt << 5;
    __syncthreads();  // protect LDS from previous iteration's readers
#pragma unroll
    for (int it = 0; it < 2; ++it) {  // stage A: 512 chunks of 8 f16
      int idx = tid + it * 256;
      int row = idx >> 2, ch = idx & 3;
      size_t gA = (size_t)(bm * 128 + row) * K + (k0 + ch * 8);
      if (A_FP32) {
        const float4* p = (const float4*)((const float*)Aptr + gA);
        float4 f0 = p[0], f1 = p[1];
        half8 h = {(_Float16)f0.x, (_Float16)f0.y, (_Float16)f0.z, (_Float16)f0.w,
                   (_Float16)f1.x, (_Float16)f1.y, (_Float16)f1.z, (_Float16)f1.w};
        *(half8*)&As[row][ch * 8] = h;
      } else {
        *(half8*)&As[row][ch * 8] = *(const half8*)((const _Float16*)Aptr + gA);
      }
    }
#pragma unroll
    for (int it = 0; it < 2; ++it) {  // stage B: 512 chunks
      int idx = tid + it * 256;
      int row = idx >> 2, ch = idx & 3;
      size_t gB = (size_t)(bn * 128 + row) * K + (k0 + ch * 8);
      *(half8*)&Bs[row][ch * 8] = *(const half8*)(Bw + gB);
    }
    __syncthreads();
    half8 a[2], b[8];
#pragma unroll
    for (int i = 0; i < 2; ++i) a[i] = *(const half8*)&As[w * 32 + i * 16 + m][q * 8];
#pragma unroll
    for (int j = 0; j < 8; ++j) b[j] = *(const half8*)&Bs[j * 16 + m][q * 8];
#pragma unroll
    for (int i = 0; i < 2; ++i)
#pragma unroll
      for (int j = 0; j < 8; ++j)
        acc[i][j] = __builtin_amdgcn_mfma_f32_16x16x32_f16(a[i], b[j], acc[i][j], 0, 0, 0);
  }

#pragma unroll
  for (int i = 0; i < 2; ++i) {
#pragma unroll
    for (int j = 0; j < 8; ++j) {
      int col = bn * 128 + j * 16 + m;
      float bv = bias[col];
#pragma unroll
      for (int rr = 0; rr < 4; ++rr) {
        int row = bm * 128 + w * 32 + i * 16 + q * 4 + rr;
        size_t orow = (OUTMODE == 1) ? ((size_t)(row & 511) * 128 + (row >> 9)) : (size_t)row;
        Cout[orow * 512 + col] = (_Float16)(acc[i][j][rr] + bv);
      }
    }
  }
}

// ---------------- recurrence: z(t) = tanh(in(t) + z(t-1) @ U^T), in pre-biased ----------------
// 128 blocks x 128 thr. Block (bt = id&7, ct = id>>3): batch rows [bt*16,+16), cols [ct*32,+32).
// U rows for the col tile live in LDS for the whole kernel (weight-stationary).
// Sync: per-batch-tile (16-block) sense-reversing barrier — blocks only depend on same-bt blocks.
__global__ __launch_bounds__(128, 1) void rnn_rec(const _Float16* __restrict__ U16,
                                                  const _Float16* __restrict__ in,
                                                  _Float16* __restrict__ zall,
                                                  unsigned* __restrict__ bar, unsigned epoch0) {
  __shared__ __align__(16) _Float16 Ut[32][520];  // 33.3 KB
  __shared__ __align__(16) _Float16 zt[16][520];  // 16.6 KB
  const int tid = threadIdx.x;
  const int bt = blockIdx.x & 7;
  const int ct = blockIdx.x >> 3;
  const int w = tid >> 6, lane = tid & 63;
  const int m = lane & 15, q = lane >> 4;
  unsigned* cnt = bar + bt * 16;
  unsigned* epoch = cnt + 1;

  for (int idx = tid; idx < 32 * 64; idx += 128) {
    int row = idx >> 6, ch = idx & 63;
    *(half8*)&Ut[row][ch * 8] = *(const half8*)&U16[(size_t)(ct * 32 + row) * 512 + ch * 8];
  }
  const int col = ct * 32 + w * 16 + m;
  unsigned target = epoch0;

  for (int s = 0; s < 512; ++s) {
    const size_t base = ((size_t)s * 128 + bt * 16) * 512;
    // issue input-term loads early (independent of the staged z)
    float inv0 = (float)in[base + (size_t)(q * 4 + 0) * 512 + col];
    float inv1 = (float)in[base + (size_t)(q * 4 + 1) * 512 + col];
    float inv2 = (float)in[base + (size_t)(q * 4 + 2) * 512 + col];
    float inv3 = (float)in[base + (size_t)(q * 4 + 3) * 512 + col];
    floatx4 acc = {0.f, 0.f, 0.f, 0.f};
    if (s > 0) {
      const size_t zb = base - (size_t)128 * 512;
      for (int idx = tid; idx < 1024; idx += 128) {  // stage z(s-1)[16 x 512]
        int row = idx >> 6, ch = idx & 63;
        *(half8*)&zt[row][ch * 8] = *(const half8*)&zall[zb + (size_t)row * 512 + ch * 8];
      }
    }
    __syncthreads();
    if (s > 0) {
#pragma unroll
      for (int kk = 0; kk < 16; ++kk) {
        half8 a = *(const half8*)&zt[m][kk * 32 + q * 8];
        half8 b = *(const half8*)&Ut[w * 16 + m][kk * 32 + q * 8];
        acc = __builtin_amdgcn_mfma_f32_16x16x32_f16(a, b, acc, 0, 0, 0);
      }
    }
    const float inv[4] = {inv0, inv1, inv2, inv3};
#pragma unroll
    for (int rr = 0; rr < 4; ++rr) {
      float v = tanhf(acc[rr] + inv[rr]);
      zall[base + (size_t)(q * 4 + rr) * 512 + col] = (_Float16)v;
    }
    if (s < 511) {
      ++target;
      __threadfence();   // release this thread's z stores device-wide (cross-XCD)
      __syncthreads();   // all threads' fences happen-before leader's arrive
      if (tid == 0) {
        unsigned v = atomicAdd(cnt, 1u);
        if (v == 15u) {
          __hip_atomic_store(cnt, 0u, __ATOMIC_RELAXED, __HIP_MEMORY_SCOPE_AGENT);
          __hip_atomic_fetch_add(epoch, 1u, __ATOMIC_RELEASE, __HIP_MEMORY_SCOPE_AGENT);
        } else {
          while (__hip_atomic_load(epoch, __ATOMIC_RELAXED, __HIP_MEMORY_SCOPE_AGENT) < target) {
          }
        }
        __threadfence();  // acquire
      }
      __syncthreads();
    }
  }
}

// ---------------- y = z1 @ V^T + V_b : [65536,512] x [512,16(9 used)] ----------------
__global__ __launch_bounds__(64) void out_gemm(const _Float16* __restrict__ z1,
                                               const _Float16* __restrict__ V16,
                                               const float* __restrict__ Vb,
                                               float* __restrict__ out) {
  __shared__ __align__(16) _Float16 zt[16][520];
  __shared__ __align__(16) _Float16 vt[16][520];
  const int tid = threadIdx.x;
  const int m = tid & 15, q = tid >> 4;
  const size_t r0 = (size_t)blockIdx.x * 16;  // rows in t-major order: r = t*128 + b
  for (int idx = tid; idx < 1024; idx += 64) {
    int row = idx >> 6, ch = idx & 63;
    *(half8*)&zt[row][ch * 8] = *(const half8*)&z1[(r0 + row) * 512 + ch * 8];
    *(half8*)&vt[row][ch * 8] = *(const half8*)&V16[(size_t)row * 512 + ch * 8];
  }
  __syncthreads();
  floatx4 acc = {0.f, 0.f, 0.f, 0.f};
#pragma unroll
  for (int kk = 0; kk < 16; ++kk) {
    half8 a = *(const half8*)&zt[m][kk * 32 + q * 8];
    half8 b = *(const half8*)&vt[m][kk * 32 + q * 8];
    acc = __builtin_amdgcn_mfma_f32_16x16x32_f16(a, b, acc, 0, 0, 0);
  }
  if (m < 9) {
#pragma unroll
    for (int rr = 0; rr < 4; ++rr) {
      size_t r = r0 + q * 4 + rr;
      size_t t = r >> 7, b = r & 127;
      out[(b * 512 + t) * 9 + m] = acc[rr] + Vb[m];
    }
  }
}

extern "C" void kernel_launch(void* const* d_in, const int* in_sizes, int n_in,
                              void* d_out, int out_size, void* d_ws, size_t ws_size,
                              hipStream_t stream) {
  const float* emb = (const float*)d_in[0];  // [128][512][256]
  const float* Ww  = (const float*)d_in[1];  // [512][256]
  const float* Wb  = (const float*)d_in[2];  // [512]
  const float* Ukw = (const float*)d_in[3];  // [2][512][512] (only [0] used)
  const float* Ukb = (const float*)d_in[4];  // [2][512]      (only [0] used)
  const float* Wkw = (const float*)d_in[5];  // [1][512][512]
  const float* Wkb = (const float*)d_in[6];  // [1][512]
  const float* Vw  = (const float*)d_in[7];  // [9][512]
  const float* Vb  = (const float*)d_in[8];  // [9]
  float* out = (float*)d_out;                // [128][512][9] f32

  char* ws = (char*)d_ws;
  _Float16* xp   = (_Float16*)(ws + 0);          // [T][B][H] f16, 64 MB (reused as z1)
  _Float16* z0   = (_Float16*)(ws + 67108864);   // 64 MB
  _Float16* c    = (_Float16*)(ws + 134217728);  // 64 MB
  _Float16* W16  = (_Float16*)(ws + 201326592);  // 256 KB
  _Float16* U16  = (_Float16*)(ws + 201588736);  // 512 KB
  _Float16* Wk16 = (_Float16*)(ws + 202113024);  // 512 KB
  _Float16* V16  = (_Float16*)(ws + 202637312);  // 16 KB
  float* bxp     = (float*)(ws + 202653696);
  float* bc      = (float*)(ws + 202655744);
  unsigned* bar  = (unsigned*)(ws + 202657792);
  _Float16* z1 = xp;  // xp is dead after layer-0 recurrence

  hipLaunchKernelGGL(cast_f32_f16, dim3(512), dim3(256), 0, stream, Ww, W16, 512 * 256);
  hipLaunchKernelGGL(cast_f32_f16, dim3(1024), dim3(256), 0, stream, Ukw, U16, 512 * 512);
  hipLaunchKernelGGL(cast_f32_f16, dim3(1024), dim3(256), 0, stream, Wkw, Wk16, 512 * 512);
  hipLaunchKernelGGL(prep_small, dim3(32), dim3(256), 0, stream, Vw, Wb, Ukb, Wkb, V16, bxp, bc, bar);
  // xp[t][b][:] = emb[b][t][:] @ W^T + (Wb + Ukb0)
  hipLaunchKernelGGL((gemm_f16<true, 1>), dim3(512, 4), dim3(256), 0, stream,
                     (const void*)emb, W16, xp, bxp, 256);
  // layer-0 recurrence
  hipLaunchKernelGGL(rnn_rec, dim3(128), dim3(128), 0, stream, U16, xp, z0, bar, 0u);
  // c = z0 @ Wk^T + (Wkb + Ukb0)
  hipLaunchKernelGGL((gemm_f16<false, 0>), dim3(512, 4), dim3(256), 0, stream,
                     (const void*)z0, Wk16, c, bc, 512);
  // layer-1 recurrence (same kernel; epoch continues at 511)
  hipLaunchKernelGGL(rnn_rec, dim3(128), dim3(128), 0, stream, U16, c, z1, bar, 511u);
  // y = z1 @ V^T + Vb
  hipLaunchKernelGGL(out_gemm, dim3(4096), dim3(64), 0, stream, z1, V16, Vb, out);
}

// Round 3
// 3190.955 us; speedup vs baseline: 3.5258x; 3.5258x over previous
//
#include <hip/hip_runtime.h>
#include <hip/hip_fp16.h>

typedef _Float16 half8 __attribute__((ext_vector_type(8)));
typedef float floatx4 __attribute__((ext_vector_type(4)));

// Problem constants: B=128, T=512, E=256, H=512, OUT=9, L=2
// Layer quirk (faithful to reference): BOTH layers use Uk_w[0] / Uk_b[0].
//
// z communication layout ("zfrag"): 16B chunks [t][bt][c16][b]:
//   c16 = h>>3 (0..63), b = batch within 16-row tile, bt = batch tile (0..7).
//   f16 offset(t, bglobal, h) = (t*8 + (b>>4))*8192 + (h>>3)*128 + (b&15)*8 + (h&7)
// Consumer lane (m=lane&15, q=lane>>4) gets its MFMA A-fragment for K-block kk
// as chunk (kk*4+q)*16+m -> two 8-byte agent-scope atomic loads. No LDS staging.

union H8 {
  half8 v;
  unsigned long long u[2];
};

// ---------------- generic f32 -> f16 cast ----------------
__global__ void cast_f32_f16(const float* __restrict__ src, _Float16* __restrict__ dst, int n) {
  int i = blockIdx.x * blockDim.x + threadIdx.x;
  if (i < n) dst[i] = (_Float16)src[i];
}

// ---------------- small prep: V pad 9->16 rows, fused biases, barrier init ----------------
__global__ void prep_small(const float* __restrict__ Vw, const float* __restrict__ Wb,
                           const float* __restrict__ Ukb, const float* __restrict__ Wkb,
                           _Float16* __restrict__ V16, float* __restrict__ bxp,
                           float* __restrict__ bc, unsigned* __restrict__ bar) {
  int i = blockIdx.x * blockDim.x + threadIdx.x;
  if (i < 16 * 512) {
    int o = i >> 9, k = i & 511;
    V16[i] = (_Float16)(o < 9 ? Vw[o * 512 + k] : 0.0f);
  }
  if (i < 512) {
    bxp[i] = Wb[i] + Ukb[i];   // layer-0 pre-activation bias
    bc[i]  = Wkb[i] + Ukb[i];  // layer-1 pre-activation bias (folded into c)
  }
  if (i < 128) bar[i] = 0u;    // 8 groups x 16 uints (cnt, epoch, pad to 64B)
}

// ---------------- tiled MFMA GEMM: C[M][512] = A[M][K] * B[512][K]^T + bias ----------------
// AMODE 0: A f16 row-major. AMODE 1: A f32 row-major. AMODE 2: A f16 zfrag (K=512, r = t*128+b).
// OUTMODE 0: out row = r. OUTMODE 1: out row = (r&511)*128 + (r>>9)  (emb [B][T] -> xp [T][B]).
template <int AMODE, int OUTMODE>
__global__ __launch_bounds__(256) void gemm_f16(const void* __restrict__ Aptr,
                                                const _Float16* __restrict__ Bw,
                                                _Float16* __restrict__ Cout,
                                                const float* __restrict__ bias, int K) {
  __shared__ __align__(16) _Float16 As[128][40];
  __shared__ __align__(16) _Float16 Bs[128][40];
  const int tid = threadIdx.x;
  const int bm = blockIdx.x, bn = blockIdx.y;
  const int w = tid >> 6, lane = tid & 63;
  const int m = lane & 15, q = lane >> 4;

  floatx4 acc[2][8];
#pragma unroll
  for (int i = 0; i < 2; ++i)
#pragma unroll
    for (int j = 0; j < 8; ++j) acc[i][j] = (floatx4){0.f, 0.f, 0.f, 0.f};

  const int nk = K >> 5;
  for (int kt = 0; kt < nk; ++kt) {
    const int k0 = kt << 5;
    __syncthreads();
#pragma unroll
    for (int it = 0; it < 2; ++it) {  // stage A
      int idx = tid + it * 256;
      int row = idx >> 2, ch = idx & 3;
      if (AMODE == 1) {
        size_t gA = (size_t)(bm * 128 + row) * K + (k0 + ch * 8);
        const float4* p = (const float4*)((const float*)Aptr + gA);
        float4 f0 = p[0], f1 = p[1];
        half8 h = {(_Float16)f0.x, (_Float16)f0.y, (_Float16)f0.z, (_Float16)f0.w,
                   (_Float16)f1.x, (_Float16)f1.y, (_Float16)f1.z, (_Float16)f1.w};
        *(half8*)&As[row][ch * 8] = h;
      } else if (AMODE == 0) {
        size_t gA = (size_t)(bm * 128 + row) * K + (k0 + ch * 8);
        *(half8*)&As[row][ch * 8] = *(const half8*)((const _Float16*)Aptr + gA);
      } else {  // zfrag layout, K==512
        int r = bm * 128 + row, t = r >> 7, b = r & 127;
        size_t off = (size_t)(t * 8 + (b >> 4)) * 8192 +
                     (size_t)((k0 + ch * 8) >> 3) * 128 + (b & 15) * 8;
        *(half8*)&As[row][ch * 8] = *(const half8*)((const _Float16*)Aptr + off);
      }
    }
#pragma unroll
    for (int it = 0; it < 2; ++it) {  // stage B
      int idx = tid + it * 256;
      int row = idx >> 2, ch = idx & 3;
      size_t gB = (size_t)(bn * 128 + row) * K + (k0 + ch * 8);
      *(half8*)&Bs[row][ch * 8] = *(const half8*)(Bw + gB);
    }
    __syncthreads();
    half8 a[2], b[8];
#pragma unroll
    for (int i = 0; i < 2; ++i) a[i] = *(const half8*)&As[w * 32 + i * 16 + m][q * 8];
#pragma unroll
    for (int j = 0; j < 8; ++j) b[j] = *(const half8*)&Bs[j * 16 + m][q * 8];
#pragma unroll
    for (int i = 0; i < 2; ++i)
#pragma unroll
      for (int j = 0; j < 8; ++j)
        acc[i][j] = __builtin_amdgcn_mfma_f32_16x16x32_f16(a[i], b[j], acc[i][j], 0, 0, 0);
  }

#pragma unroll
  for (int i = 0; i < 2; ++i) {
#pragma unroll
    for (int j = 0; j < 8; ++j) {
      int col = bn * 128 + j * 16 + m;
      float bv = bias[col];
#pragma unroll
      for (int rr = 0; rr < 4; ++rr) {
        int row = bm * 128 + w * 32 + i * 16 + q * 4 + rr;
        size_t orow = (OUTMODE == 1) ? ((size_t)(row & 511) * 128 + (row >> 9)) : (size_t)row;
        Cout[orow * 512 + col] = (_Float16)(acc[i][j][rr] + bv);
      }
    }
  }
}

// ---------------- recurrence: z(t) = tanh(in(t) + z(t-1) @ U^T), in pre-biased ----------------
// 128 blocks x 128 thr. Block (bt = id&7, ct = id>>3): batch rows [bt*16,+16), cols [ct*32,+32).
// z exchanged through agent-scope relaxed atomics (coherence point) in zfrag layout.
// No fences, no L2 flush. Barrier: per-bt-group (16 blocks) epoch counter, leader thread only.
// Ordering: agent stores -> __syncthreads (drains vmcnt) -> leader release epoch bump ->
// waiter spin -> __syncthreads -> agent loads (coherence point; bypass stale L1/L2).
__global__ __launch_bounds__(128, 1) void rnn_rec3(const _Float16* __restrict__ U16,
                                                   const _Float16* __restrict__ in,
                                                   _Float16* __restrict__ zf,
                                                   unsigned* __restrict__ bar, unsigned epoch0) {
  __shared__ __align__(16) _Float16 Ut[32][520];  // 33.3 KB, weight-stationary
  __shared__ __align__(16) _Float16 zo[16][40];   // 1.3 KB transpose buffer
  const int tid = threadIdx.x;
  const int bt = blockIdx.x & 7;
  const int ct = blockIdx.x >> 3;
  const int w = tid >> 6, lane = tid & 63;
  const int m = lane & 15, q = lane >> 4;
  unsigned* cnt = bar + bt * 16;
  unsigned* epoch = cnt + 1;

  for (int idx = tid; idx < 32 * 64; idx += 128) {  // U tile -> LDS (plain cached loads)
    int row = idx >> 6, ch = idx & 63;
    *(half8*)&Ut[row][ch * 8] = *(const half8*)&U16[(size_t)(ct * 32 + row) * 512 + ch * 8];
  }

  // producer store mapping: half = tid&1, b = (tid>>1)&15, cq = tid>>5 (0..3)
  const int p_half = tid & 1, p_b = (tid >> 1) & 15, p_cq = tid >> 5;
  const int col = ct * 32 + w * 16 + m;  // global h for input term
  const int col_l = w * 16 + m;          // local col 0..31
  const size_t in_row = (size_t)(bt * 16) * 512 + col;

  unsigned target = epoch0;

  for (int s = 0; s < 512; ++s) {
    // input term (plain cached loads; compiler inserts waitcnt before use)
    const _Float16* ip = in + (size_t)s * 65536 + in_row;
    float inv0 = (float)ip[0 * 512];
    float inv1 = (float)ip[1 * 512 + (size_t)(q * 4) * 512 - (q ? 512 : 0)];  // dummy-free below
    // (simple and explicit instead:)
    inv0 = (float)ip[(size_t)(q * 4 + 0) * 512];
    inv1 = (float)ip[(size_t)(q * 4 + 1) * 512];
    float inv2 = (float)ip[(size_t)(q * 4 + 2) * 512];
    float inv3 = (float)ip[(size_t)(q * 4 + 3) * 512];

    floatx4 acc0 = {0.f, 0.f, 0.f, 0.f}, acc1 = {0.f, 0.f, 0.f, 0.f};
    if (s > 0) {
      // A-fragments of z(s-1): 32 x 8B agent-scope atomic loads from the coherence point
      unsigned long long* ab =
          (unsigned long long*)((char*)zf + (((size_t)(s - 1) * 8 + bt) * 1024 + q * 16 + m) * 16);
      H8 afr[16];
#pragma unroll
      for (int kk = 0; kk < 16; ++kk) {
        unsigned long long* p = ab + (size_t)kk * 128;  // kk*1024 bytes
        afr[kk].u[0] = __hip_atomic_load(p, __ATOMIC_RELAXED, __HIP_MEMORY_SCOPE_AGENT);
        afr[kk].u[1] = __hip_atomic_load(p + 1, __ATOMIC_RELAXED, __HIP_MEMORY_SCOPE_AGENT);
      }
#pragma unroll
      for (int kk = 0; kk < 16; kk += 2) {
        half8 b0 = *(const half8*)&Ut[w * 16 + m][kk * 32 + q * 8];
        half8 b1 = *(const half8*)&Ut[w * 16 + m][(kk + 1) * 32 + q * 8];
        acc0 = __builtin_amdgcn_mfma_f32_16x16x32_f16(afr[kk].v, b0, acc0, 0, 0, 0);
        acc1 = __builtin_amdgcn_mfma_f32_16x16x32_f16(afr[kk + 1].v, b1, acc1, 0, 0, 0);
      }
    }
    const float inv[4] = {inv0, inv1, inv2, inv3};
#pragma unroll
    for (int rr = 0; rr < 4; ++rr) {
      float v = tanhf(acc0[rr] + acc1[rr] + inv[rr]);
      zo[q * 4 + rr][col_l] = (_Float16)v;  // transpose staging
    }
    __syncthreads();  // (b) zo published
    {
      unsigned long long pv = *(const unsigned long long*)&zo[p_b][p_cq * 8 + p_half * 4];
      unsigned long long* dst =
          (unsigned long long*)((char*)zf +
                                ((((size_t)s * 8 + bt) * 64 + (size_t)(ct * 4 + p_cq)) * 16 + p_b) *
                                    16 +
                                p_half * 8);
      __hip_atomic_store(dst, pv, __ATOMIC_RELAXED, __HIP_MEMORY_SCOPE_AGENT);
    }
    __syncthreads();  // (c) drains vmcnt(0): all agent stores at coherence point
    if (s < 511) {
      ++target;
      if (tid == 0) {
        unsigned v = __hip_atomic_fetch_add(cnt, 1u, __ATOMIC_RELAXED, __HIP_MEMORY_SCOPE_AGENT);
        if (v == 15u) {
          __hip_atomic_store(cnt, 0u, __ATOMIC_RELAXED, __HIP_MEMORY_SCOPE_AGENT);
          __hip_atomic_fetch_add(epoch, 1u, __ATOMIC_RELEASE, __HIP_MEMORY_SCOPE_AGENT);
        } else {
          while (__hip_atomic_load(epoch, __ATOMIC_RELAXED, __HIP_MEMORY_SCOPE_AGENT) < target) {
          }
        }
      }
      __syncthreads();  // (d) release waiters; consumers then issue agent loads
    }
  }
}

// ---------------- y = z1 @ V^T + V_b : rows t-major, z1 in zfrag layout ----------------
__global__ __launch_bounds__(64) void out_gemm(const _Float16* __restrict__ z1,
                                               const _Float16* __restrict__ V16,
                                               const float* __restrict__ Vb,
                                               float* __restrict__ out) {
  __shared__ __align__(16) _Float16 zt[16][520];
  __shared__ __align__(16) _Float16 vt[16][520];
  const int tid = threadIdx.x;
  const int m = tid & 15, q = tid >> 4;
  const size_t r0 = (size_t)blockIdx.x * 16;  // r = t*128 + b
  for (int idx = tid; idx < 1024; idx += 64) {
    int row = idx >> 6, ch = idx & 63;
    int r = (int)(r0 + row), t = r >> 7, b = r & 127;
    size_t off = (size_t)(t * 8 + (b >> 4)) * 8192 + (size_t)ch * 128 + (b & 15) * 8;
    *(half8*)&zt[row][ch * 8] = *(const half8*)&z1[off];
    *(half8*)&vt[row][ch * 8] = *(const half8*)&V16[(size_t)row * 512 + ch * 8];
  }
  __syncthreads();
  floatx4 acc = {0.f, 0.f, 0.f, 0.f};
#pragma unroll
  for (int kk = 0; kk < 16; ++kk) {
    half8 a = *(const half8*)&zt[m][kk * 32 + q * 8];
    half8 b = *(const half8*)&vt[m][kk * 32 + q * 8];
    acc = __builtin_amdgcn_mfma_f32_16x16x32_f16(a, b, acc, 0, 0, 0);
  }
  if (m < 9) {
#pragma unroll
    for (int rr = 0; rr < 4; ++rr) {
      size_t r = r0 + q * 4 + rr;
      size_t t = r >> 7, b = r & 127;
      out[(b * 512 + t) * 9 + m] = acc[rr] + Vb[m];
    }
  }
}

extern "C" void kernel_launch(void* const* d_in, const int* in_sizes, int n_in,
                              void* d_out, int out_size, void* d_ws, size_t ws_size,
                              hipStream_t stream) {
  const float* emb = (const float*)d_in[0];  // [128][512][256]
  const float* Ww  = (const float*)d_in[1];  // [512][256]
  const float* Wb  = (const float*)d_in[2];  // [512]
  const float* Ukw = (const float*)d_in[3];  // [2][512][512] (only [0] used)
  const float* Ukb = (const float*)d_in[4];  // [2][512]      (only [0] used)
  const float* Wkw = (const float*)d_in[5];  // [1][512][512]
  const float* Wkb = (const float*)d_in[6];  // [1][512]
  const float* Vw  = (const float*)d_in[7];  // [9][512]
  const float* Vb  = (const float*)d_in[8];  // [9]
  float* out = (float*)d_out;                // [128][512][9] f32

  char* ws = (char*)d_ws;
  _Float16* xp   = (_Float16*)(ws + 0);          // [T][B][H] f16 t-major (reused as z1f)
  _Float16* z0f  = (_Float16*)(ws + 67108864);   // zfrag layout, 64 MB
  _Float16* c    = (_Float16*)(ws + 134217728);  // [T][B][H] f16 t-major
  _Float16* W16  = (_Float16*)(ws + 201326592);
  _Float16* U16  = (_Float16*)(ws + 201588736);
  _Float16* Wk16 = (_Float16*)(ws + 202113024);
  _Float16* V16  = (_Float16*)(ws + 202637312);
  float* bxp     = (float*)(ws + 202653696);
  float* bc      = (float*)(ws + 202655744);
  unsigned* bar  = (unsigned*)(ws + 202657792);
  _Float16* z1f = xp;  // xp dead after layer-0 recurrence

  hipLaunchKernelGGL(cast_f32_f16, dim3(512), dim3(256), 0, stream, Ww, W16, 512 * 256);
  hipLaunchKernelGGL(cast_f32_f16, dim3(1024), dim3(256), 0, stream, Ukw, U16, 512 * 512);
  hipLaunchKernelGGL(cast_f32_f16, dim3(1024), dim3(256), 0, stream, Wkw, Wk16, 512 * 512);
  hipLaunchKernelGGL(prep_small, dim3(32), dim3(256), 0, stream, Vw, Wb, Ukb, Wkb, V16, bxp, bc, bar);
  // xp[t][b][:] = emb[b][t][:] @ W^T + (Wb + Ukb0)
  hipLaunchKernelGGL((gemm_f16<1, 1>), dim3(512, 4), dim3(256), 0, stream,
                     (const void*)emb, W16, xp, bxp, 256);
  // layer-0 recurrence -> z0f (zfrag)
  hipLaunchKernelGGL(rnn_rec3, dim3(128), dim3(128), 0, stream, U16, xp, z0f, bar, 0u);
  // c = z0 @ Wk^T + (Wkb + Ukb0)   (A in zfrag layout)
  hipLaunchKernelGGL((gemm_f16<2, 0>), dim3(512, 4), dim3(256), 0, stream,
                     (const void*)z0f, Wk16, c, bc, 512);
  // layer-1 recurrence -> z1f (zfrag; epoch continues at 511)
  hipLaunchKernelGGL(rnn_rec3, dim3(128), dim3(128), 0, stream, U16, c, z1f, bar, 511u);
  // y = z1 @ V^T + Vb
  hipLaunchKernelGGL(out_gemm, dim3(4096), dim3(64), 0, stream, z1f, V16, Vb, out);
}

// Round 4
// 2195.253 us; speedup vs baseline: 5.1250x; 1.4536x over previous
//
#include <hip/hip_runtime.h>
#include <hip/hip_fp16.h>

typedef _Float16 half8 __attribute__((ext_vector_type(8)));
typedef float floatx4 __attribute__((ext_vector_type(4)));

// B=128, T=512, E=256, H=512, OUT=9, L=2. Quirk: both layers use Uk_w[0]/Uk_b[0].
//
// zfrag layout (R3-verified): 16B chunks [t][bt][c16][b]:
//   f16 offset(t,bglobal,h) = (t*8 + (b>>4))*8192 + (h>>3)*128 + (b&15)*8 + (h&7)
// chunk index within (t,bt): c = c16*16 + b15, c16 = h>>3 (0..63), b15 = b&15.
// Consumer lane (m=lane&15,q=lane>>4) A-frag for K-block kk = chunk (kk*4+q)*16+m.

union H8 {
  half8 v;
  unsigned long long u[2];
};

// ---------------- prep: V pad 9->16, fused biases, zero flags ----------------
__global__ void prep_small(const float* __restrict__ Vw, const float* __restrict__ Wb,
                           const float* __restrict__ Ukb, const float* __restrict__ Wkb,
                           _Float16* __restrict__ V16, float* __restrict__ bxp,
                           float* __restrict__ bc, unsigned* __restrict__ flags) {
  int i = blockIdx.x * blockDim.x + threadIdx.x;
  if (i < 16 * 512) {
    int o = i >> 9, k = i & 511;
    V16[i] = (_Float16)(o < 9 ? Vw[o * 512 + k] : 0.0f);
  }
  if (i < 512) {
    bxp[i] = Wb[i] + Ukb[i];   // layer-0 pre-activation bias (folded into xp)
    bc[i]  = Wkb[i] + Ukb[i];  // layer-1 pre-activation bias (added in-kernel)
  }
  for (int j = i; j < 2 * 512 * 8 * 4; j += 8192) flags[j] = 0u;  // [2][512][8][4]
}

// ---------------- tiled MFMA GEMM: C[M][512] = A[M][K] * B[512][K]^T + bias ----------------
// AMODE 0: A f16 row-major. AMODE 1: A f32 row-major. BMODE 0: B f16. BMODE 1: B f32.
// OUTMODE 0: out row = r. OUTMODE 1: out row = (r&511)*128 + (r>>9)  (emb [B][T] -> xp [T][B]).
template <int AMODE, int BMODE, int OUTMODE>
__global__ __launch_bounds__(256) void gemm_f16(const void* __restrict__ Aptr,
                                                const void* __restrict__ Bptr,
                                                _Float16* __restrict__ Cout,
                                                const float* __restrict__ bias, int K) {
  __shared__ __align__(16) _Float16 As[128][40];
  __shared__ __align__(16) _Float16 Bs[128][40];
  const int tid = threadIdx.x;
  const int bm = blockIdx.x, bn = blockIdx.y;
  const int w = tid >> 6, lane = tid & 63;
  const int m = lane & 15, q = lane >> 4;

  floatx4 acc[2][8];
#pragma unroll
  for (int i = 0; i < 2; ++i)
#pragma unroll
    for (int j = 0; j < 8; ++j) acc[i][j] = (floatx4){0.f, 0.f, 0.f, 0.f};

  const int nk = K >> 5;
  for (int kt = 0; kt < nk; ++kt) {
    const int k0 = kt << 5;
    __syncthreads();
#pragma unroll
    for (int it = 0; it < 2; ++it) {  // stage A
      int idx = tid + it * 256;
      int row = idx >> 2, ch = idx & 3;
      size_t gA = (size_t)(bm * 128 + row) * K + (k0 + ch * 8);
      if (AMODE == 1) {
        const float4* p = (const float4*)((const float*)Aptr + gA);
        float4 f0 = p[0], f1 = p[1];
        half8 h = {(_Float16)f0.x, (_Float16)f0.y, (_Float16)f0.z, (_Float16)f0.w,
                   (_Float16)f1.x, (_Float16)f1.y, (_Float16)f1.z, (_Float16)f1.w};
        *(half8*)&As[row][ch * 8] = h;
      } else {
        *(half8*)&As[row][ch * 8] = *(const half8*)((const _Float16*)Aptr + gA);
      }
    }
#pragma unroll
    for (int it = 0; it < 2; ++it) {  // stage B
      int idx = tid + it * 256;
      int row = idx >> 2, ch = idx & 3;
      size_t gB = (size_t)(bn * 128 + row) * K + (k0 + ch * 8);
      if (BMODE == 1) {
        const float4* p = (const float4*)((const float*)Bptr + gB);
        float4 f0 = p[0], f1 = p[1];
        half8 h = {(_Float16)f0.x, (_Float16)f0.y, (_Float16)f0.z, (_Float16)f0.w,
                   (_Float16)f1.x, (_Float16)f1.y, (_Float16)f1.z, (_Float16)f1.w};
        *(half8*)&Bs[row][ch * 8] = h;
      } else {
        *(half8*)&Bs[row][ch * 8] = *(const half8*)((const _Float16*)Bptr + gB);
      }
    }
    __syncthreads();
    half8 a[2], b[8];
#pragma unroll
    for (int i = 0; i < 2; ++i) a[i] = *(const half8*)&As[w * 32 + i * 16 + m][q * 8];
#pragma unroll
    for (int j = 0; j < 8; ++j) b[j] = *(const half8*)&Bs[j * 16 + m][q * 8];
#pragma unroll
    for (int i = 0; i < 2; ++i)
#pragma unroll
      for (int j = 0; j < 8; ++j)
        acc[i][j] = __builtin_amdgcn_mfma_f32_16x16x32_f16(a[i], b[j], acc[i][j], 0, 0, 0);
  }

#pragma unroll
  for (int i = 0; i < 2; ++i) {
#pragma unroll
    for (int j = 0; j < 8; ++j) {
      int col = bn * 128 + j * 16 + m;
      float bv = bias[col];
#pragma unroll
      for (int rr = 0; rr < 4; ++rr) {
        int row = bm * 128 + w * 32 + i * 16 + q * 4 + rr;
        size_t orow = (OUTMODE == 1) ? ((size_t)(row & 511) * 128 + (row >> 9)) : (size_t)row;
        Cout[orow * 512 + col] = (_Float16)(acc[i][j][rr] + bv);
      }
    }
  }
}

// ---------------- fused 2-layer recurrence, pipelined across layers ----------------
// 64 blocks x 256 thr. layer = blk>>5, bt = blk&7, ct = (blk>>3)&3.
// Block covers batch rows [bt*16,+16), cols [ct*128,+128). Weights (U, and Wk for
// layer 1) fully register-resident (B-fragments). z exchanged via zfrag chunks with
// relaxed agent atomics; per-producer flags; consumers stage A-frags via LDS once/block.
__device__ __forceinline__ void waitflags(const unsigned* a, const unsigned* b, int lane) {
  for (;;) {
    unsigned v = 1u;
    if (lane < 4)
      v = __hip_atomic_load(a + lane, __ATOMIC_RELAXED, __HIP_MEMORY_SCOPE_AGENT);
    else if (b != nullptr && lane >= 8 && lane < 12)
      v = __hip_atomic_load(b + (lane - 8), __ATOMIC_RELAXED, __HIP_MEMORY_SCOPE_AGENT);
    if (__ballot(v != 0u) == ~0ull) return;
  }
}

__global__ __launch_bounds__(256, 1) void rnn_fused(const float* __restrict__ Uw,
                                                    const float* __restrict__ Wkw,
                                                    const _Float16* __restrict__ xp,
                                                    _Float16* __restrict__ z0f,
                                                    _Float16* __restrict__ z1f,
                                                    const float* __restrict__ bc,
                                                    unsigned* __restrict__ flags) {
  __shared__ __align__(16) _Float16 az0[8192];  // staged A chunks: 16 KB
  __shared__ __align__(16) _Float16 az1[8192];  // layer-1: z1(s-1)
  __shared__ __align__(16) _Float16 zo[16][136];
  const int tid = threadIdx.x;
  const int layer = blockIdx.x >> 5;
  const int bt = blockIdx.x & 7;
  const int ct = (blockIdx.x >> 3) & 3;
  const int lane = tid & 63, w = tid >> 6;
  const int m = lane & 15, q = lane >> 4;
  const int colbase = ct * 128 + w * 32;  // wave's 2 tiles: cols colbase+t*16+m

  // preload weight B-fragments from fp32 (one-time)
  half8 ufr[2][16], wfr[2][16];
#pragma unroll
  for (int t = 0; t < 2; ++t) {
    const float* up = Uw + (size_t)(colbase + t * 16 + m) * 512 + q * 8;
    const float* wp = Wkw + (size_t)(colbase + t * 16 + m) * 512 + q * 8;
#pragma unroll
    for (int kk = 0; kk < 16; ++kk) {
      float4 f0 = *(const float4*)(up + kk * 32);
      float4 f1 = *(const float4*)(up + kk * 32 + 4);
      ufr[t][kk] = (half8){(_Float16)f0.x, (_Float16)f0.y, (_Float16)f0.z, (_Float16)f0.w,
                           (_Float16)f1.x, (_Float16)f1.y, (_Float16)f1.z, (_Float16)f1.w};
      if (layer) {
        float4 g0 = *(const float4*)(wp + kk * 32);
        float4 g1 = *(const float4*)(wp + kk * 32 + 4);
        wfr[t][kk] = (half8){(_Float16)g0.x, (_Float16)g0.y, (_Float16)g0.z, (_Float16)g0.w,
                             (_Float16)g1.x, (_Float16)g1.y, (_Float16)g1.z, (_Float16)g1.w};
      }
    }
  }
  float bias[2] = {0.f, 0.f};
  if (layer) { bias[0] = bc[colbase + m]; bias[1] = bc[colbase + 16 + m]; }

  unsigned* f0 = flags;                 // layer-0 flags [512][8][4]
  unsigned* f1 = flags + 512 * 8 * 4;   // layer-1 flags
  const int c16l = tid >> 4, b15 = tid & 15;
  _Float16* zoutf = layer ? z1f : z0f;

  for (int s = 0; s < 512; ++s) {
    // layer-0 input term: issue early (latency covered by flag poll)
    float pin[8];
    if (layer == 0) {
      const _Float16* xb = xp + (size_t)s * 65536 + (size_t)(bt * 16) * 512;
#pragma unroll
      for (int t = 0; t < 2; ++t)
#pragma unroll
        for (int rr = 0; rr < 4; ++rr)
          pin[t * 4 + rr] = (float)xb[(size_t)(q * 4 + rr) * 512 + colbase + t * 16 + m];
    }

    // wait for producers, stage A chunks into LDS (coalesced 16B agent loads)
    if (layer == 0) {
      if (s > 0) {
        waitflags(f0 + ((s - 1) * 8 + bt) * 4, nullptr, lane);
        const unsigned long long* src =
            (const unsigned long long*)((const char*)z0f + ((size_t)(s - 1) * 8 + bt) * 16384);
#pragma unroll
        for (int j = 0; j < 4; ++j) {
          int c = tid + j * 256;
          H8 t8;
          t8.u[0] = __hip_atomic_load(src + c * 2, __ATOMIC_RELAXED, __HIP_MEMORY_SCOPE_AGENT);
          t8.u[1] = __hip_atomic_load(src + c * 2 + 1, __ATOMIC_RELAXED, __HIP_MEMORY_SCOPE_AGENT);
          *(half8*)&az0[c * 8] = t8.v;
        }
      }
    } else {
      waitflags(f0 + (s * 8 + bt) * 4, s > 0 ? f1 + ((s - 1) * 8 + bt) * 4 : nullptr, lane);
      const unsigned long long* s0 =
          (const unsigned long long*)((const char*)z0f + ((size_t)s * 8 + bt) * 16384);
#pragma unroll
      for (int j = 0; j < 4; ++j) {
        int c = tid + j * 256;
        H8 t8;
        t8.u[0] = __hip_atomic_load(s0 + c * 2, __ATOMIC_RELAXED, __HIP_MEMORY_SCOPE_AGENT);
        t8.u[1] = __hip_atomic_load(s0 + c * 2 + 1, __ATOMIC_RELAXED, __HIP_MEMORY_SCOPE_AGENT);
        *(half8*)&az0[c * 8] = t8.v;
      }
      if (s > 0) {
        const unsigned long long* s1 =
            (const unsigned long long*)((const char*)z1f + ((size_t)(s - 1) * 8 + bt) * 16384);
#pragma unroll
        for (int j = 0; j < 4; ++j) {
          int c = tid + j * 256;
          H8 t8;
          t8.u[0] = __hip_atomic_load(s1 + c * 2, __ATOMIC_RELAXED, __HIP_MEMORY_SCOPE_AGENT);
          t8.u[1] = __hip_atomic_load(s1 + c * 2 + 1, __ATOMIC_RELAXED, __HIP_MEMORY_SCOPE_AGENT);
          *(half8*)&az1[c * 8] = t8.v;
        }
      }
    }
    __syncthreads();  // az* published (drains staging stores' deps)

    floatx4 acc[2][2];
    acc[0][0] = (floatx4){0.f, 0.f, 0.f, 0.f};
    acc[1][0] = (floatx4){0.f, 0.f, 0.f, 0.f};
    acc[0][1] = (floatx4){bias[0], bias[0], bias[0], bias[0]};
    acc[1][1] = (floatx4){bias[1], bias[1], bias[1], bias[1]};
    if (layer == 0) {
      if (s > 0) {
#pragma unroll
        for (int kk = 0; kk < 16; ++kk) {
          half8 a = *(const half8*)&az0[((kk * 4 + q) * 16 + m) * 8];
          acc[0][kk & 1] = __builtin_amdgcn_mfma_f32_16x16x32_f16(a, ufr[0][kk], acc[0][kk & 1], 0, 0, 0);
          acc[1][kk & 1] = __builtin_amdgcn_mfma_f32_16x16x32_f16(a, ufr[1][kk], acc[1][kk & 1], 0, 0, 0);
        }
      }
    } else {
#pragma unroll
      for (int kk = 0; kk < 16; ++kk) {
        half8 a0 = *(const half8*)&az0[((kk * 4 + q) * 16 + m) * 8];
        acc[0][1] = __builtin_amdgcn_mfma_f32_16x16x32_f16(a0, wfr[0][kk], acc[0][1], 0, 0, 0);
        acc[1][1] = __builtin_amdgcn_mfma_f32_16x16x32_f16(a0, wfr[1][kk], acc[1][1], 0, 0, 0);
      }
      if (s > 0) {
#pragma unroll
        for (int kk = 0; kk < 16; ++kk) {
          half8 a1 = *(const half8*)&az1[((kk * 4 + q) * 16 + m) * 8];
          acc[0][0] = __builtin_amdgcn_mfma_f32_16x16x32_f16(a1, ufr[0][kk], acc[0][0], 0, 0, 0);
          acc[1][0] = __builtin_amdgcn_mfma_f32_16x16x32_f16(a1, ufr[1][kk], acc[1][0], 0, 0, 0);
        }
      }
    }

    // tanh(x) = 1 - 2/(exp2(x*2/ln2)+1); exp2 -> v_exp_f32, rcp -> v_rcp_f32
#pragma unroll
    for (int t = 0; t < 2; ++t)
#pragma unroll
      for (int rr = 0; rr < 4; ++rr) {
        float x = acc[t][0][rr] + acc[t][1][rr] + (layer ? 0.f : pin[t * 4 + rr]);
        float e = __builtin_exp2f(x * 2.885390081777927f);
        float r = 1.f - 2.f * __builtin_amdgcn_rcpf(e + 1.f);
        zo[q * 4 + rr][w * 32 + t * 16 + m] = (_Float16)r;
      }
    __syncthreads();  // zo published

    {  // chunk store to zfrag (agent scope): one 16B chunk per thread
      H8 pv;
      pv.v = *(const half8*)&zo[b15][c16l * 8];
      unsigned long long* dst =
          (unsigned long long*)((char*)zoutf +
                                (((size_t)s * 8 + bt) * 1024 + (size_t)(ct * 16 + c16l) * 16 + b15) * 16);
      __hip_atomic_store(dst, pv.u[0], __ATOMIC_RELAXED, __HIP_MEMORY_SCOPE_AGENT);
      __hip_atomic_store(dst + 1, pv.u[1], __ATOMIC_RELAXED, __HIP_MEMORY_SCOPE_AGENT);
    }
    __syncthreads();  // vmcnt(0) drained before barrier -> all chunks at coherence point
    if (tid == 0)
      __hip_atomic_store((layer ? f1 : f0) + (s * 8 + bt) * 4 + ct, 1u, __ATOMIC_RELAXED,
                         __HIP_MEMORY_SCOPE_AGENT);
  }
}

// ---------------- y = z1 @ V^T + V_b : rows t-major, z1 in zfrag layout ----------------
__global__ __launch_bounds__(64) void out_gemm(const _Float16* __restrict__ z1,
                                               const _Float16* __restrict__ V16,
                                               const float* __restrict__ Vb,
                                               float* __restrict__ out) {
  __shared__ __align__(16) _Float16 zt[16][520];
  __shared__ __align__(16) _Float16 vt[16][520];
  const int tid = threadIdx.x;
  const int m = tid & 15, q = tid >> 4;
  const size_t r0 = (size_t)blockIdx.x * 16;  // r = t*128 + b
  for (int idx = tid; idx < 1024; idx += 64) {
    int row = idx >> 6, ch = idx & 63;
    int r = (int)(r0 + row), t = r >> 7, b = r & 127;
    size_t off = (size_t)(t * 8 + (b >> 4)) * 8192 + (size_t)ch * 128 + (b & 15) * 8;
    *(half8*)&zt[row][ch * 8] = *(const half8*)&z1[off];
    *(half8*)&vt[row][ch * 8] = *(const half8*)&V16[(size_t)row * 512 + ch * 8];
  }
  __syncthreads();
  floatx4 acc = {0.f, 0.f, 0.f, 0.f};
#pragma unroll
  for (int kk = 0; kk < 16; ++kk) {
    half8 a = *(const half8*)&zt[m][kk * 32 + q * 8];
    half8 b = *(const half8*)&vt[m][kk * 32 + q * 8];
    acc = __builtin_amdgcn_mfma_f32_16x16x32_f16(a, b, acc, 0, 0, 0);
  }
  if (m < 9) {
#pragma unroll
    for (int rr = 0; rr < 4; ++rr) {
      size_t r = r0 + q * 4 + rr;
      size_t t = r >> 7, b = r & 127;
      out[(b * 512 + t) * 9 + m] = acc[rr] + Vb[m];
    }
  }
}

extern "C" void kernel_launch(void* const* d_in, const int* in_sizes, int n_in,
                              void* d_out, int out_size, void* d_ws, size_t ws_size,
                              hipStream_t stream) {
  const float* emb = (const float*)d_in[0];  // [128][512][256]
  const float* Ww  = (const float*)d_in[1];  // [512][256]
  const float* Wb  = (const float*)d_in[2];  // [512]
  const float* Ukw = (const float*)d_in[3];  // [2][512][512] (only [0] used)
  const float* Ukb = (const float*)d_in[4];  // [2][512]      (only [0] used)
  const float* Wkw = (const float*)d_in[5];  // [1][512][512]
  const float* Wkb = (const float*)d_in[6];  // [1][512]
  const float* Vw  = (const float*)d_in[7];  // [9][512]
  const float* Vb  = (const float*)d_in[8];  // [9]
  float* out = (float*)d_out;                // [128][512][9] f32

  char* ws = (char*)d_ws;
  _Float16* xp   = (_Float16*)(ws + 0);          // [T][B][H] f16 t-major, 64 MB
  _Float16* z0f  = (_Float16*)(ws + 67108864);   // zfrag, 64 MB
  _Float16* z1f  = (_Float16*)(ws + 134217728);  // zfrag, 64 MB
  _Float16* V16  = (_Float16*)(ws + 201326592);  // 16 KB
  float* bxp     = (float*)(ws + 201342976);
  float* bc      = (float*)(ws + 201345024);
  unsigned* flags = (unsigned*)(ws + 201347072);  // [2][512][8][4] = 128 KB

  hipLaunchKernelGGL(prep_small, dim3(32), dim3(256), 0, stream,
                     Vw, Wb, Ukb, Wkb, V16, bxp, bc, flags);
  // xp[t][b][:] = emb[b][t][:] @ W^T + (Wb + Ukb0)   (A f32, B f32)
  hipLaunchKernelGGL((gemm_f16<1, 1, 1>), dim3(512, 4), dim3(256), 0, stream,
                     (const void*)emb, (const void*)Ww, xp, bxp, 256);
  // fused, pipelined 2-layer recurrence (layer-1 consumes z0 flags, no middle GEMM)
  hipLaunchKernelGGL(rnn_fused, dim3(64), dim3(256), 0, stream,
                     Ukw, Wkw, xp, z0f, z1f, bc, flags);
  // y = z1 @ V^T + Vb
  hipLaunchKernelGGL(out_gemm, dim3(4096), dim3(64), 0, stream, z1f, V16, Vb, out);
}

// Round 5
// 1748.486 us; speedup vs baseline: 6.4345x; 1.2555x over previous
//
#include <hip/hip_runtime.h>
#include <hip/hip_fp16.h>

typedef _Float16 half8 __attribute__((ext_vector_type(8)));
typedef float floatx4 __attribute__((ext_vector_type(4)));

// B=128, T=512, E=256, H=512, OUT=9, L=2. Quirk: both layers use Uk_w[0]/Uk_b[0].
//
// zfrag layout (R3/R4-verified): 16B chunks [t][bt][c16][b15]:
//   chunk index within (t,bt) tile: c = c16*16 + b15, c16 = h>>3, b15 = b&15.
// Consumer lane (m,q) A-frag for K-block kk = chunk (kk*4+q)*16+m.
//
// ENCODED STORAGE: z is stored as enc = z + 2 (f16, range [1,3], bits
// 0x3C00..0x4200). Poison 0xAA bytes (-0.052) and zeros fall outside -> a
// granule is valid iff its low f16 is in range. No flags, no fences, no
// ordering: consumers poll the data itself via 8B relaxed agent atomics.
// Decode is free: z@U = (z+2)@U - 2*rowsum(U); folded into constants.

union H8 { half8 v; unsigned long long u[2]; };

__device__ __forceinline__ unsigned long long agload(const unsigned long long* p) {
  return __hip_atomic_load(p, __ATOMIC_RELAXED, __HIP_MEMORY_SCOPE_AGENT);
}
__device__ __forceinline__ void agstore(unsigned long long* p, unsigned long long v) {
  __hip_atomic_store(p, v, __ATOMIC_RELAXED, __HIP_MEMORY_SCOPE_AGENT);
}
__device__ __forceinline__ bool valid16(unsigned long long u) {
  return (unsigned)((unsigned)(u & 0xFFFFull) - 0x3C00u) <= 0x600u;  // f16 in [1.0, 3.0]
}

// ---------------- prep: V pad, fused biases, f16-rounded weight row-sums ----------------
__global__ void prep_small(const float* __restrict__ Vw, const float* __restrict__ Vb,
                           const float* __restrict__ Wb, const float* __restrict__ Ukb,
                           const float* __restrict__ Wkb, const float* __restrict__ Ukw,
                           const float* __restrict__ Wkw, _Float16* __restrict__ V16,
                           float* __restrict__ bxp, float* __restrict__ bc,
                           float* __restrict__ sums) {
  int i = blockIdx.x * blockDim.x + threadIdx.x;
  if (i < 16 * 512) {
    int o = i >> 9, k = i & 511;
    V16[i] = (_Float16)(o < 9 ? Vw[o * 512 + k] : 0.0f);
  }
  if (i < 512) {
    bxp[i] = Wb[i] + Ukb[i];   // layer-0 pre-activation bias (folded into xp)
    bc[i]  = Wkb[i] + Ukb[i];  // layer-1 pre-activation bias
  }
  if (i < 1024) {  // sums[0..511]=rowsum f16(U); [512..1023]=rowsum f16(Wk)
    const float* row = (i < 512) ? Ukw + (size_t)i * 512 : Wkw + (size_t)(i - 512) * 512;
    float s = 0.f;
    for (int k = 0; k < 512; k += 4) {
      float4 v = *(const float4*)(row + k);
      s += (float)(_Float16)v.x + (float)(_Float16)v.y + (float)(_Float16)v.z + (float)(_Float16)v.w;
    }
    sums[i] = s;
  } else if (i < 1040) {  // sums[1024..1039] = out bias: Vb - 2*rowsum f16(V)
    int o = i - 1024;
    float s = 0.f;
    if (o < 9) {
      const float* row = Vw + (size_t)o * 512;
      for (int k = 0; k < 512; k += 4) {
        float4 v = *(const float4*)(row + k);
        s += (float)(_Float16)v.x + (float)(_Float16)v.y + (float)(_Float16)v.z + (float)(_Float16)v.w;
      }
    }
    sums[i] = (o < 9 ? Vb[o] : 0.f) - 2.f * s;
  }
}

// ---------------- xp GEMM: xp[t][b][:] = emb[b][t][:] @ W^T + (Wb+Ukb0), f32 in, f16 out ----
__global__ __launch_bounds__(256) void gemm_xp(const float* __restrict__ Aptr,
                                               const float* __restrict__ Bptr,
                                               _Float16* __restrict__ Cout,
                                               const float* __restrict__ bias) {
  const int K = 256;
  __shared__ __align__(16) _Float16 As[128][40];
  __shared__ __align__(16) _Float16 Bs[128][40];
  const int tid = threadIdx.x;
  const int bm = blockIdx.x, bn = blockIdx.y;
  const int w = tid >> 6, lane = tid & 63;
  const int m = lane & 15, q = lane >> 4;

  floatx4 acc[2][8];
#pragma unroll
  for (int i = 0; i < 2; ++i)
#pragma unroll
    for (int j = 0; j < 8; ++j) acc[i][j] = (floatx4){0.f, 0.f, 0.f, 0.f};

  for (int kt = 0; kt < (K >> 5); ++kt) {
    const int k0 = kt << 5;
    __syncthreads();
#pragma unroll
    for (int it = 0; it < 2; ++it) {
      int idx = tid + it * 256;
      int row = idx >> 2, ch = idx & 3;
      size_t gA = (size_t)(bm * 128 + row) * K + (k0 + ch * 8);
      const float4* p = (const float4*)(Aptr + gA);
      float4 f0 = p[0], f1 = p[1];
      *(half8*)&As[row][ch * 8] =
          (half8){(_Float16)f0.x, (_Float16)f0.y, (_Float16)f0.z, (_Float16)f0.w,
                  (_Float16)f1.x, (_Float16)f1.y, (_Float16)f1.z, (_Float16)f1.w};
      size_t gB = (size_t)(bn * 128 + row) * K + (k0 + ch * 8);
      const float4* pb = (const float4*)(Bptr + gB);
      float4 g0 = pb[0], g1 = pb[1];
      *(half8*)&Bs[row][ch * 8] =
          (half8){(_Float16)g0.x, (_Float16)g0.y, (_Float16)g0.z, (_Float16)g0.w,
                  (_Float16)g1.x, (_Float16)g1.y, (_Float16)g1.z, (_Float16)g1.w};
    }
    __syncthreads();
    half8 a[2], b[8];
#pragma unroll
    for (int i = 0; i < 2; ++i) a[i] = *(const half8*)&As[w * 32 + i * 16 + m][q * 8];
#pragma unroll
    for (int j = 0; j < 8; ++j) b[j] = *(const half8*)&Bs[j * 16 + m][q * 8];
#pragma unroll
    for (int i = 0; i < 2; ++i)
#pragma unroll
      for (int j = 0; j < 8; ++j)
        acc[i][j] = __builtin_amdgcn_mfma_f32_16x16x32_f16(a[i], b[j], acc[i][j], 0, 0, 0);
  }
#pragma unroll
  for (int i = 0; i < 2; ++i)
#pragma unroll
    for (int j = 0; j < 8; ++j) {
      int col = bn * 128 + j * 16 + m;
      float bv = bias[col];
#pragma unroll
      for (int rr = 0; rr < 4; ++rr) {
        int row = bm * 128 + w * 32 + i * 16 + q * 4 + rr;  // row = b*512 + t
        size_t orow = (size_t)(row & 511) * 128 + (row >> 9);  // -> t*128 + b
        Cout[orow * 512 + col] = (_Float16)(acc[i][j][rr] + bv);
      }
    }
}

// ---------------- poll+load one 16KB z tile into LDS (validity = data range) --------------
template <int SLEEP>
__device__ __forceinline__ void stage_tile(const _Float16* srcTile, _Float16* dst, int tid) {
  const unsigned long long* src = (const unsigned long long*)srcTile;
  unsigned long long g[8];
#pragma unroll
  for (int j = 0; j < 4; ++j) {  // first pass: 8 unconditional loads, pipelined (~1 RT)
    g[2 * j] = agload(src + 2 * (tid + j * 256));
    g[2 * j + 1] = agload(src + 2 * (tid + j * 256) + 1);
  }
  unsigned need = 0;
#pragma unroll
  for (int i = 0; i < 8; ++i)
    if (!valid16(g[i])) need |= (1u << i);
  while (need) {
    if (SLEEP) __builtin_amdgcn_s_sleep(1);
#pragma unroll
    for (int i = 0; i < 8; ++i)
      if (need & (1u << i)) {
        unsigned long long v = agload(src + 2 * (tid + (i >> 1) * 256) + (i & 1));
        if (valid16(v)) { g[i] = v; need &= ~(1u << i); }
      }
  }
#pragma unroll
  for (int j = 0; j < 4; ++j) {
    H8 t;
    t.u[0] = g[2 * j];
    t.u[1] = g[2 * j + 1];
    *(half8*)&dst[(tid + j * 256) * 8] = t.v;
  }
}

// ---------------- fused 2-layer recurrence, data-polling, encoded z ----------------
// 64 blocks x 256 thr. layer = blk>>5, bt = blk&7, ct = (blk>>3)&3.
// Block: batch rows [bt*16,+16), cols [ct*128,+128). U (and Wk for L1) register-resident.
__global__ __launch_bounds__(256, 1) void rnn_fused2(const float* __restrict__ Uw,
                                                     const float* __restrict__ Wkw,
                                                     const _Float16* __restrict__ xp,
                                                     _Float16* __restrict__ z0f,
                                                     _Float16* __restrict__ z1f,
                                                     const float* __restrict__ bc,
                                                     const float* __restrict__ sums) {
  __shared__ __align__(16) _Float16 az[8192];   // own-layer z_prev tile (16 KB)
  __shared__ __align__(16) _Float16 azs[8192];  // L1: z0(s) shadow tile
  __shared__ __align__(16) _Float16 zo[16][136];
  const int tid = threadIdx.x;
  const int layer = blockIdx.x >> 5, bt = blockIdx.x & 7, ct = (blockIdx.x >> 3) & 3;
  const int lane = tid & 63, w = tid >> 6, m = lane & 15, q = lane >> 4;
  const int colbase = ct * 128 + w * 32;

  half8 ufr[2][16], wfr[2][16];
#pragma unroll
  for (int t = 0; t < 2; ++t) {
    const float* up = Uw + (size_t)(colbase + t * 16 + m) * 512 + q * 8;
    const float* wp = Wkw + (size_t)(colbase + t * 16 + m) * 512 + q * 8;
#pragma unroll
    for (int kk = 0; kk < 16; ++kk) {
      float4 f0 = *(const float4*)(up + kk * 32), f1 = *(const float4*)(up + kk * 32 + 4);
      ufr[t][kk] = (half8){(_Float16)f0.x, (_Float16)f0.y, (_Float16)f0.z, (_Float16)f0.w,
                           (_Float16)f1.x, (_Float16)f1.y, (_Float16)f1.z, (_Float16)f1.w};
      if (layer) {
        float4 g0 = *(const float4*)(wp + kk * 32), g1 = *(const float4*)(wp + kk * 32 + 4);
        wfr[t][kk] = (half8){(_Float16)g0.x, (_Float16)g0.y, (_Float16)g0.z, (_Float16)g0.w,
                             (_Float16)g1.x, (_Float16)g1.y, (_Float16)g1.z, (_Float16)g1.w};
      }
    }
  }
  const float corrU[2] = {-2.f * sums[colbase + m], -2.f * sums[colbase + 16 + m]};
  float cw[2] = {0.f, 0.f};
  if (layer) {
    cw[0] = -2.f * sums[512 + colbase + m] + bc[colbase + m];
    cw[1] = -2.f * sums[512 + colbase + 16 + m] + bc[colbase + 16 + m];
  }

  const int c16l = tid >> 4, b15 = tid & 15;
  _Float16* zout = layer ? z1f : z0f;

  if (layer) stage_tile<1>(z0f + (size_t)bt * 8192, azs, tid);  // z0(0)

  for (int s = 0; s < 512; ++s) {
    float pin[8];
    if (layer == 0) {  // input term: issue early, consumed after MFMAs
      const _Float16* xb = xp + (size_t)s * 65536 + (size_t)(bt * 16) * 512;
#pragma unroll
      for (int t = 0; t < 2; ++t)
#pragma unroll
        for (int rr = 0; rr < 4; ++rr)
          pin[t * 4 + rr] = (float)xb[(size_t)(q * 4 + rr) * 512 + colbase + t * 16 + m];
    }

    floatx4 wk[2];
    wk[0] = (floatx4){0.f, 0.f, 0.f, 0.f};
    wk[1] = (floatx4){0.f, 0.f, 0.f, 0.f};
    if (layer) {
      __syncthreads();  // (A) publish azs (prev tail); zo WAR
      unsigned long long g[8];
      unsigned need = 0;
      const unsigned long long* src =
          (const unsigned long long*)(z1f + ((size_t)(s - 1) * 8 + bt) * 8192);
      if (s > 0) {  // first-pass z1(s-1) loads, in flight during Wk MFMAs below
#pragma unroll
        for (int j = 0; j < 4; ++j) {
          g[2 * j] = agload(src + 2 * (tid + j * 256));
          g[2 * j + 1] = agload(src + 2 * (tid + j * 256) + 1);
        }
      }
#pragma unroll
      for (int kk = 0; kk < 16; ++kk) {  // Wk @ z0(s) (encoded; corrected via cw)
        half8 a = *(const half8*)&azs[((kk * 4 + q) * 16 + m) * 8];
        wk[0] = __builtin_amdgcn_mfma_f32_16x16x32_f16(a, wfr[0][kk], wk[0], 0, 0, 0);
        wk[1] = __builtin_amdgcn_mfma_f32_16x16x32_f16(a, wfr[1][kk], wk[1], 0, 0, 0);
      }
      if (s > 0) {
#pragma unroll
        for (int i = 0; i < 8; ++i)
          if (!valid16(g[i])) need |= (1u << i);
        while (need) {
#pragma unroll
          for (int i = 0; i < 8; ++i)
            if (need & (1u << i)) {
              unsigned long long v = agload(src + 2 * (tid + (i >> 1) * 256) + (i & 1));
              if (valid16(v)) { g[i] = v; need &= ~(1u << i); }
            }
        }
#pragma unroll
        for (int j = 0; j < 4; ++j) {
          H8 t;
          t.u[0] = g[2 * j];
          t.u[1] = g[2 * j + 1];
          *(half8*)&az[(tid + j * 256) * 8] = t.v;
        }
      }
    } else {
      if (s > 0) stage_tile<0>(z0f + ((size_t)(s - 1) * 8 + bt) * 8192, az, tid);
    }
    __syncthreads();  // (A2) publish az; (covers zo WAR for L0)

    floatx4 acc[2][2];
    acc[0][0] = (floatx4){0.f, 0.f, 0.f, 0.f};
    acc[0][1] = (floatx4){0.f, 0.f, 0.f, 0.f};
    acc[1][0] = (floatx4){0.f, 0.f, 0.f, 0.f};
    acc[1][1] = (floatx4){0.f, 0.f, 0.f, 0.f};
    if (s > 0) {
#pragma unroll
      for (int kk = 0; kk < 16; ++kk) {  // U @ z_prev (encoded; corrected via corrU)
        half8 a = *(const half8*)&az[((kk * 4 + q) * 16 + m) * 8];
        acc[0][kk & 1] = __builtin_amdgcn_mfma_f32_16x16x32_f16(a, ufr[0][kk], acc[0][kk & 1], 0, 0, 0);
        acc[1][kk & 1] = __builtin_amdgcn_mfma_f32_16x16x32_f16(a, ufr[1][kk], acc[1][kk & 1], 0, 0, 0);
      }
    }
#pragma unroll
    for (int t = 0; t < 2; ++t)
#pragma unroll
      for (int rr = 0; rr < 4; ++rr) {
        float x = layer ? (wk[t][rr] + cw[t]) : pin[t * 4 + rr];
        if (s > 0) x += acc[t][0][rr] + acc[t][1][rr] + corrU[t];
        // enc = tanh(x) + 2 = 3 - 2/(exp2(x*2/ln2)+1)
        float e = __builtin_exp2f(x * 2.885390081777927f);
        float enc = 3.f - 2.f * __builtin_amdgcn_rcpf(e + 1.f);
        zo[q * 4 + rr][w * 32 + t * 16 + m] = (_Float16)enc;
      }
    __syncthreads();  // (B) zo published
    {
      H8 pv;
      pv.v = *(const half8*)&zo[b15][c16l * 8];
      unsigned long long* dst =
          (unsigned long long*)((char*)zout +
                                (((size_t)s * 8 + bt) * 1024 + (size_t)(ct * 16 + c16l) * 16 + b15) * 16);
      agstore(dst, pv.u[0]);
      agstore(dst + 1, pv.u[1]);
    }
    if (layer && s < 511)  // shadow: stage z0(s+1) for next step's Wk part
      stage_tile<1>(z0f + ((size_t)(s + 1) * 8 + bt) * 8192, azs, tid);
  }
}

// ---------------- y = z1 @ V^T + bco : z1 encoded in zfrag layout ----------------
__global__ __launch_bounds__(64) void out_gemm(const _Float16* __restrict__ z1,
                                               const _Float16* __restrict__ V16,
                                               const float* __restrict__ bco,
                                               float* __restrict__ out) {
  __shared__ __align__(16) _Float16 zt[16][520];
  __shared__ __align__(16) _Float16 vt[16][520];
  const int tid = threadIdx.x;
  const int m = tid & 15, q = tid >> 4;
  const size_t r0 = (size_t)blockIdx.x * 16;  // r = t*128 + b
  for (int idx = tid; idx < 1024; idx += 64) {
    int row = idx >> 6, ch = idx & 63;
    int r = (int)(r0 + row), t = r >> 7, b = r & 127;
    size_t off = (size_t)(t * 8 + (b >> 4)) * 8192 + (size_t)ch * 128 + (b & 15) * 8;
    *(half8*)&zt[row][ch * 8] = *(const half8*)&z1[off];
    *(half8*)&vt[row][ch * 8] = *(const half8*)&V16[(size_t)row * 512 + ch * 8];
  }
  __syncthreads();
  floatx4 acc = {0.f, 0.f, 0.f, 0.f};
#pragma unroll
  for (int kk = 0; kk < 16; ++kk) {
    half8 a = *(const half8*)&zt[m][kk * 32 + q * 8];
    half8 b = *(const half8*)&vt[m][kk * 32 + q * 8];
    acc = __builtin_amdgcn_mfma_f32_16x16x32_f16(a, b, acc, 0, 0, 0);
  }
  if (m < 9) {
#pragma unroll
    for (int rr = 0; rr < 4; ++rr) {
      size_t r = r0 + q * 4 + rr;
      size_t t = r >> 7, b = r & 127;
      out[(b * 512 + t) * 9 + m] = acc[rr] + bco[m];
    }
  }
}

extern "C" void kernel_launch(void* const* d_in, const int* in_sizes, int n_in,
                              void* d_out, int out_size, void* d_ws, size_t ws_size,
                              hipStream_t stream) {
  const float* emb = (const float*)d_in[0];  // [128][512][256]
  const float* Ww  = (const float*)d_in[1];  // [512][256]
  const float* Wb  = (const float*)d_in[2];  // [512]
  const float* Ukw = (const float*)d_in[3];  // [2][512][512] (only [0] used)
  const float* Ukb = (const float*)d_in[4];  // [2][512]      (only [0] used)
  const float* Wkw = (const float*)d_in[5];  // [1][512][512]
  const float* Wkb = (const float*)d_in[6];  // [1][512]
  const float* Vw  = (const float*)d_in[7];  // [9][512]
  const float* Vb  = (const float*)d_in[8];  // [9]
  float* out = (float*)d_out;                // [128][512][9] f32

  char* ws = (char*)d_ws;
  _Float16* xp   = (_Float16*)(ws + 0);          // [T][B][H] f16 t-major, 64 MB
  _Float16* z0f  = (_Float16*)(ws + 67108864);   // zfrag (encoded), 64 MB
  _Float16* z1f  = (_Float16*)(ws + 134217728);  // zfrag (encoded), 64 MB
  _Float16* V16  = (_Float16*)(ws + 201326592);  // 16 KB
  float* bxp     = (float*)(ws + 201342976);
  float* bc      = (float*)(ws + 201345024);
  float* sums    = (float*)(ws + 201347072);     // SU[512], SW[512], bco[16]

  hipLaunchKernelGGL(prep_small, dim3(32), dim3(256), 0, stream,
                     Vw, Vb, Wb, Ukb, Wkb, Ukw, Wkw, V16, bxp, bc, sums);
  hipLaunchKernelGGL(gemm_xp, dim3(512, 4), dim3(256), 0, stream, emb, Ww, xp, bxp);
  hipLaunchKernelGGL(rnn_fused2, dim3(64), dim3(256), 0, stream,
                     Ukw, Wkw, xp, z0f, z1f, bc, sums);
  hipLaunchKernelGGL(out_gemm, dim3(4096), dim3(64), 0, stream, z1f, V16, sums + 1024, out);
}